// Round 1
// baseline (3480.141 us; speedup 1.0000x reference)
//
#include <hip/hip_runtime.h>
#include <math.h>

#define N 2048
#define D 256
#define H 8
#define DK 32
#define L 4
#define DFF 1024
#define NEDGE 5

// ---------------- embed: x[n,:] = node_emb[node_types[n],:] ----------------
__global__ __launch_bounds__(256) void k_embed(const int* __restrict__ nt,
                                               const float* __restrict__ emb,
                                               float* __restrict__ x) {
  int n = blockIdx.x, d = threadIdx.x;
  x[n * D + d] = emb[nt[n] * D + d];
}

// ---------------- tiled fp32 GEMM: C = A(MxK) @ B(KxN) [+bias][+gelu] ------
// 64x64 tile per 256-thread block, 4x4 per thread, K-tile 16.
__global__ __launch_bounds__(256) void k_gemm(const float* __restrict__ A,
                                              const float* __restrict__ B,
                                              float* __restrict__ C,
                                              int M, int Nn, int K,
                                              const float* __restrict__ bias,
                                              int gelu) {
  __shared__ float As[16][65];
  __shared__ float Bs[16][65];
  int tid = threadIdx.x;
  int bm = blockIdx.y * 64, bn = blockIdx.x * 64;
  int tr = tid >> 4, tc = tid & 15;
  float acc[4][4] = {};
  for (int k0 = 0; k0 < K; k0 += 16) {
#pragma unroll
    for (int i = 0; i < 4; ++i) {
      int idx = tid + i * 256;  // 0..1023
      int m = idx >> 4, kk = idx & 15;
      As[kk][m] = A[(size_t)(bm + m) * K + k0 + kk];
      int k2 = idx >> 6, n2 = idx & 63;
      Bs[k2][n2] = B[(size_t)(k0 + k2) * Nn + bn + n2];
    }
    __syncthreads();
#pragma unroll
    for (int kk = 0; kk < 16; ++kk) {
      float a[4], b[4];
#pragma unroll
      for (int u = 0; u < 4; ++u) a[u] = As[kk][tr * 4 + u];
#pragma unroll
      for (int u = 0; u < 4; ++u) b[u] = Bs[kk][tc * 4 + u];
#pragma unroll
      for (int i = 0; i < 4; ++i)
#pragma unroll
        for (int j = 0; j < 4; ++j) acc[i][j] = fmaf(a[i], b[j], acc[i][j]);
    }
    __syncthreads();
  }
#pragma unroll
  for (int i = 0; i < 4; ++i) {
    int row = bm + tr * 4 + i;
#pragma unroll
    for (int j = 0; j < 4; ++j) {
      int col = bn + tc * 4 + j;
      float v = acc[i][j];
      if (bias) v += bias[col];
      if (gelu) v = 0.5f * v * (1.0f + erff(v * 0.70710678118654752f));
      C[(size_t)row * Nn + col] = v;
    }
  }
}

// ---------------- attention: one wave per (head,row), full-row softmax -----
// Q,K,V are (N, D) with head h occupying columns [h*DK, (h+1)*DK).
// Out[i, h*DK+d] = sum_j softmax_j(q_i.k_j*scale + eb[eidx[i,j],h]) * V[j,h*DK+d]
__global__ __launch_bounds__(256) void k_attn(const float* __restrict__ Q,
                                              const float* __restrict__ K,
                                              const float* __restrict__ V,
                                              const int* __restrict__ eidx,
                                              const float* __restrict__ eb,
                                              float* __restrict__ Out) {
  __shared__ float p_s[4][N];
  __shared__ float ebh_s[NEDGE];
  int wave = threadIdx.x >> 6;
  int lane = threadIdx.x & 63;
  int h = blockIdx.y;
  int row = blockIdx.x * 4 + wave;

  if (threadIdx.x < NEDGE) ebh_s[threadIdx.x] = eb[threadIdx.x * H + h];

  float q[DK];
  const float* qp = Q + (size_t)row * D + h * DK;
#pragma unroll
  for (int d = 0; d < DK; ++d) q[d] = qp[d];
  __syncthreads();

  const float scale = 0.17677669529663688f;  // 1/sqrt(32)
  float sc[N / 64];
  float mymax = -INFINITY;
#pragma unroll 4
  for (int jj = 0; jj < N / 64; ++jj) {
    int j = jj * 64 + lane;
    const float* kp = K + (size_t)j * D + h * DK;
    float s = 0.f;
#pragma unroll
    for (int d = 0; d < DK; ++d) s = fmaf(q[d], kp[d], s);
    s = s * scale + ebh_s[eidx[(size_t)row * N + j]];
    sc[jj] = s;
    mymax = fmaxf(mymax, s);
  }
#pragma unroll
  for (int off = 32; off; off >>= 1) mymax = fmaxf(mymax, __shfl_xor(mymax, off));
  float sum = 0.f;
#pragma unroll
  for (int jj = 0; jj < N / 64; ++jj) {
    float e = __expf(sc[jj] - mymax);
    sc[jj] = e;
    sum += e;
  }
#pragma unroll
  for (int off = 32; off; off >>= 1) sum += __shfl_xor(sum, off);
  float inv = 1.0f / sum;
#pragma unroll
  for (int jj = 0; jj < N / 64; ++jj) p_s[wave][jj * 64 + lane] = sc[jj] * inv;
  __syncthreads();

  // accumulate out[d] = sum_j p[j] * V[j, h*DK+d]; lanes split d(32) x half(2)
  int d = lane & 31, half = lane >> 5;
  float a = 0.f;
  const float* vp = V + h * DK + d;
  for (int j = half * (N / 2); j < (half + 1) * (N / 2); ++j) {
    a = fmaf(p_s[wave][j], vp[(size_t)j * D], a);
  }
  a += __shfl_xor(a, 32);
  if (lane < 32) Out[(size_t)row * D + h * DK + d] = a;
}

// ---------------- residual + layernorm (in-place safe): out = LN(x+y)*g+b --
__global__ __launch_bounds__(256) void k_add_ln(const float* __restrict__ x,
                                                const float* __restrict__ y,
                                                const float* __restrict__ g,
                                                const float* __restrict__ b,
                                                float* __restrict__ outx) {
  __shared__ float s[256];
  int row = blockIdx.x, d = threadIdx.x;
  float t = x[(size_t)row * D + d] + y[(size_t)row * D + d];
  s[d] = t;
  __syncthreads();
#pragma unroll
  for (int off = 128; off; off >>= 1) {
    if (d < off) s[d] += s[d + off];
    __syncthreads();
  }
  float mean = s[0] * (1.0f / D);
  __syncthreads();
  float c = t - mean;
  s[d] = c * c;
  __syncthreads();
#pragma unroll
  for (int off = 128; off; off >>= 1) {
    if (d < off) s[d] += s[d + off];
    __syncthreads();
  }
  float var = s[0] * (1.0f / D);
  float r = rsqrtf(var + 1e-5f);
  outx[(size_t)row * D + d] = c * r * g[d] + b[d];
}

// ---------------- pool (mean & max over rows) + final projection -----------
__global__ __launch_bounds__(256) void k_pool(const float* __restrict__ x,
                                              const float* __restrict__ Wr,
                                              const float* __restrict__ br,
                                              float* __restrict__ out) {
  __shared__ float pooled[2 * D];
  int d = threadIdx.x;
  float mean = 0.f, mx = -INFINITY;
  for (int n = 0; n < N; ++n) {
    float v = x[(size_t)n * D + d];
    mean += v;
    mx = fmaxf(mx, v);
  }
  pooled[d] = mean * (1.0f / N);
  pooled[D + d] = mx;
  __syncthreads();
  float acc = br[d];
  for (int k2 = 0; k2 < 2 * D; ++k2) acc = fmaf(pooled[k2], Wr[(size_t)k2 * D + d], acc);
  out[d] = acc;
}

extern "C" void kernel_launch(void* const* d_in, const int* in_sizes, int n_in,
                              void* d_out, int out_size, void* d_ws, size_t ws_size,
                              hipStream_t stream) {
  const int* node_types = (const int*)d_in[0];
  const int* eidx = (const int*)d_in[1];
  const float* node_emb = (const float*)d_in[2];
  const float* Wq = (const float*)d_in[3];
  const float* Wk = (const float*)d_in[4];
  const float* Wv = (const float*)d_in[5];
  const float* Wo = (const float*)d_in[6];
  const float* bo = (const float*)d_in[7];
  const float* eb = (const float*)d_in[8];
  const float* W1 = (const float*)d_in[9];
  const float* b1 = (const float*)d_in[10];
  const float* W2 = (const float*)d_in[11];
  const float* b2 = (const float*)d_in[12];
  const float* g1 = (const float*)d_in[13];
  const float* be1 = (const float*)d_in[14];
  const float* g2 = (const float*)d_in[15];
  const float* be2 = (const float*)d_in[16];
  const float* Wr = (const float*)d_in[17];
  const float* br = (const float*)d_in[18];
  float* out = (float*)d_out;

  float* x = (float*)d_ws;
  float* q = x + (size_t)N * D;
  float* k = q + (size_t)N * D;
  float* v = k + (size_t)N * D;
  float* ao = v + (size_t)N * D;
  float* tmp = ao + (size_t)N * D;
  float* hb = tmp + (size_t)N * D;  // N x DFF

  k_embed<<<N, 256, 0, stream>>>(node_types, node_emb, x);

  for (int l = 0; l < L; ++l) {
    const float* wq = Wq + (size_t)l * D * D;
    const float* wk = Wk + (size_t)l * D * D;
    const float* wv = Wv + (size_t)l * D * D;
    const float* wo = Wo + (size_t)l * D * D;
    const float* w1 = W1 + (size_t)l * D * DFF;
    const float* w2 = W2 + (size_t)l * DFF * D;

    dim3 gdd(D / 64, N / 64);
    k_gemm<<<gdd, 256, 0, stream>>>(x, wq, q, N, D, D, nullptr, 0);
    k_gemm<<<gdd, 256, 0, stream>>>(x, wk, k, N, D, D, nullptr, 0);
    k_gemm<<<gdd, 256, 0, stream>>>(x, wv, v, N, D, D, nullptr, 0);

    k_attn<<<dim3(N / 4, H), 256, 0, stream>>>(q, k, v, eidx, eb + (size_t)l * NEDGE * H, ao);

    k_gemm<<<gdd, 256, 0, stream>>>(ao, wo, tmp, N, D, D, bo + (size_t)l * D, 0);
    k_add_ln<<<N, 256, 0, stream>>>(x, tmp, g1 + (size_t)l * D, be1 + (size_t)l * D, x);

    k_gemm<<<dim3(DFF / 64, N / 64), 256, 0, stream>>>(x, w1, hb, N, DFF, D, b1 + (size_t)l * DFF, 1);
    k_gemm<<<gdd, 256, 0, stream>>>(hb, w2, tmp, N, D, DFF, b2 + (size_t)l * D, 0);
    k_add_ln<<<N, 256, 0, stream>>>(x, tmp, g2 + (size_t)l * D, be2 + (size_t)l * D, x);
  }

  k_pool<<<1, 256, 0, stream>>>(x, Wr, br, out);
}

// Round 2
// 1461.857 us; speedup vs baseline: 2.3806x; 2.3806x over previous
//
#include <hip/hip_runtime.h>
#include <math.h>

#define N 2048
#define D 256
#define H 8
#define DK 32
#define L 4
#define DFF 1024
#define NEDGE 5

typedef short short8 __attribute__((ext_vector_type(8)));
typedef float floatx4 __attribute__((ext_vector_type(4)));

__device__ __forceinline__ unsigned short f2bf(float f) {
  unsigned int u = __float_as_uint(f);
  u += 0x7fffu + ((u >> 16) & 1u);
  return (unsigned short)(u >> 16);
}

// ---------------- embed: x[n,:] = node_emb[node_types[n],:] ----------------
__global__ __launch_bounds__(256) void k_embed(const int* __restrict__ nt,
                                               const float* __restrict__ emb,
                                               float* __restrict__ x) {
  int n = blockIdx.x, d = threadIdx.x;
  x[n * D + d] = emb[nt[n] * D + d];
}

// ---------------- tiled fp32 GEMM: C = A(MxK) @ B(KxN) [+bias][+gelu] ------
__global__ __launch_bounds__(256) void k_gemm(const float* __restrict__ A,
                                              const float* __restrict__ B,
                                              float* __restrict__ C,
                                              int M, int Nn, int K,
                                              const float* __restrict__ bias,
                                              int gelu) {
  __shared__ float As[16][65];
  __shared__ float Bs[16][65];
  int tid = threadIdx.x;
  int bm = blockIdx.y * 64, bn = blockIdx.x * 64;
  int tr = tid >> 4, tc = tid & 15;
  float acc[4][4] = {};
  for (int k0 = 0; k0 < K; k0 += 16) {
#pragma unroll
    for (int i = 0; i < 4; ++i) {
      int idx = tid + i * 256;
      int m = idx >> 4, kk = idx & 15;
      As[kk][m] = A[(size_t)(bm + m) * K + k0 + kk];
      int k2 = idx >> 6, n2 = idx & 63;
      Bs[k2][n2] = B[(size_t)(k0 + k2) * Nn + bn + n2];
    }
    __syncthreads();
#pragma unroll
    for (int kk = 0; kk < 16; ++kk) {
      float a[4], b[4];
#pragma unroll
      for (int u = 0; u < 4; ++u) a[u] = As[kk][tr * 4 + u];
#pragma unroll
      for (int u = 0; u < 4; ++u) b[u] = Bs[kk][tc * 4 + u];
#pragma unroll
      for (int i = 0; i < 4; ++i)
#pragma unroll
        for (int j = 0; j < 4; ++j) acc[i][j] = fmaf(a[i], b[j], acc[i][j]);
    }
    __syncthreads();
  }
#pragma unroll
  for (int i = 0; i < 4; ++i) {
    int row = bm + tr * 4 + i;
#pragma unroll
    for (int j = 0; j < 4; ++j) {
      int col = bn + tc * 4 + j;
      float v = acc[i][j];
      if (bias) v += bias[col];
      if (gelu) v = 0.5f * v * (1.0f + erff(v * 0.70710678118654752f));
      C[(size_t)row * Nn + col] = v;
    }
  }
}

// ---------------- MFMA flash attention -------------------------------------
// Block = 128 threads (2 waves). Each wave: 16 Q-rows of one head.
// j-tiles of 64: QK^T = 4x mfma_f32_16x16x32_bf16, online softmax in C-layout,
// P -> LDS (bf16, A-layout read), PV = 4 MFMAs vs LDS-transposed V tile.
#define KS_STR 40  // bf16 units; 80 B rows (16B-aligned, <=2-way banks on frag reads)
#define VT_STR 72  // 144 B rows
#define PB_STR 72

__global__ __launch_bounds__(128) void k_attn(const float* __restrict__ Q,
                                              const float* __restrict__ K,
                                              const float* __restrict__ V,
                                              const int* __restrict__ eidx,
                                              const float* __restrict__ eb,
                                              float* __restrict__ Out) {
  __shared__ unsigned short Ks_s[64 * KS_STR];
  __shared__ unsigned short Vt_s[32 * VT_STR];
  __shared__ unsigned short Pb_s[2][16 * PB_STR];
  __shared__ float ebh_s[NEDGE];

  const int tid = threadIdx.x;
  const int h = blockIdx.y;
  const int w = tid >> 6;
  const int lane = tid & 63;
  const int quad = lane >> 4;
  const int c16 = lane & 15;
  const int r0w = (blockIdx.x * 2 + w) * 16;

  if (tid < NEDGE) ebh_s[tid] = eb[tid * H + h];

  // Q fragment (A-operand): lane holds Q[r0w + c16][quad*8 .. +7] as bf16
  short8 aq;
  {
    const float* qp = Q + (size_t)(r0w + c16) * D + h * DK + quad * 8;
    float4 q0 = *(const float4*)qp;
    float4 q1 = *(const float4*)(qp + 4);
    aq[0] = (short)f2bf(q0.x); aq[1] = (short)f2bf(q0.y);
    aq[2] = (short)f2bf(q0.z); aq[3] = (short)f2bf(q0.w);
    aq[4] = (short)f2bf(q1.x); aq[5] = (short)f2bf(q1.y);
    aq[6] = (short)f2bf(q1.z); aq[7] = (short)f2bf(q1.w);
  }

  float mrow[4] = {-INFINITY, -INFINITY, -INFINITY, -INFINITY};
  float lrow[4] = {0.f, 0.f, 0.f, 0.f};
  floatx4 O0 = {0.f, 0.f, 0.f, 0.f};
  floatx4 O1 = {0.f, 0.f, 0.f, 0.f};

  const float scale = 0.17677669529663688f;  // 1/sqrt(32)
  const int jrow = tid >> 1;   // staging: row 0..63
  const int jhalf = tid & 1;   // 16-float half of the 32-wide head slice

  for (int j0 = 0; j0 < N; j0 += 64) {
    __syncthreads();  // all frag reads of previous tile done before restage
    {
      const float* kp = K + (size_t)(j0 + jrow) * D + h * DK + jhalf * 16;
      float4 a0 = *(const float4*)(kp);
      float4 a1 = *(const float4*)(kp + 4);
      float4 a2 = *(const float4*)(kp + 8);
      float4 a3 = *(const float4*)(kp + 12);
      float kv[16] = {a0.x, a0.y, a0.z, a0.w, a1.x, a1.y, a1.z, a1.w,
                      a2.x, a2.y, a2.z, a2.w, a3.x, a3.y, a3.z, a3.w};
      short8 kb0, kb1;
#pragma unroll
      for (int c = 0; c < 8; ++c) kb0[c] = (short)f2bf(kv[c]);
#pragma unroll
      for (int c = 0; c < 8; ++c) kb1[c] = (short)f2bf(kv[8 + c]);
      *(short8*)&Ks_s[jrow * KS_STR + jhalf * 16] = kb0;
      *(short8*)&Ks_s[jrow * KS_STR + jhalf * 16 + 8] = kb1;

      const float* vp = V + (size_t)(j0 + jrow) * D + h * DK + jhalf * 16;
      float4 b0 = *(const float4*)(vp);
      float4 b1 = *(const float4*)(vp + 4);
      float4 b2 = *(const float4*)(vp + 8);
      float4 b3 = *(const float4*)(vp + 12);
      float vv[16] = {b0.x, b0.y, b0.z, b0.w, b1.x, b1.y, b1.z, b1.w,
                      b2.x, b2.y, b2.z, b2.w, b3.x, b3.y, b3.z, b3.w};
      int dbase = jhalf * 16;
#pragma unroll
      for (int c = 0; c < 16; ++c)
        Vt_s[(dbase + c) * VT_STR + jrow] = f2bf(vv[c]);
    }
    __syncthreads();

    // ---- QK^T: 4 MFMAs (16 j each) ----
    floatx4 Sc[4];
#pragma unroll
    for (int t = 0; t < 4; ++t) {
      short8 bk = *(const short8*)&Ks_s[(t * 16 + c16) * KS_STR + quad * 8];
      floatx4 z = {0.f, 0.f, 0.f, 0.f};
      Sc[t] = __builtin_amdgcn_mfma_f32_16x16x32_bf16(aq, bk, z, 0, 0, 0);
    }
    // ---- scale + edge bias (C-layout: col=c16, row=quad*4+e) ----
    float s[4][4];
#pragma unroll
    for (int t = 0; t < 4; ++t) {
#pragma unroll
      for (int e = 0; e < 4; ++e) {
        int row = r0w + quad * 4 + e;
        int ei = eidx[(size_t)row * N + j0 + t * 16 + c16];
        s[t][e] = Sc[t][e] * scale + ebh_s[ei];
      }
    }
    // ---- online softmax: 4 rows per lane, reduced over 16 cols ----
#pragma unroll
    for (int e = 0; e < 4; ++e) {
      float tm = fmaxf(fmaxf(s[0][e], s[1][e]), fmaxf(s[2][e], s[3][e]));
      tm = fmaxf(tm, __shfl_xor(tm, 1));
      tm = fmaxf(tm, __shfl_xor(tm, 2));
      tm = fmaxf(tm, __shfl_xor(tm, 4));
      tm = fmaxf(tm, __shfl_xor(tm, 8));
      float mn = fmaxf(mrow[e], tm);
      float alpha = __expf(mrow[e] - mn);  // first tile: exp(-inf)=0
      mrow[e] = mn;
      float ps = 0.f;
#pragma unroll
      for (int t = 0; t < 4; ++t) {
        float p = __expf(s[t][e] - mn);
        s[t][e] = p;
        ps += p;
      }
      ps += __shfl_xor(ps, 1);
      ps += __shfl_xor(ps, 2);
      ps += __shfl_xor(ps, 4);
      ps += __shfl_xor(ps, 8);
      lrow[e] = lrow[e] * alpha + ps;
      O0[e] *= alpha;
      O1[e] *= alpha;
    }
    // ---- P (C-layout) -> LDS bf16, to be read back in A-layout ----
#pragma unroll
    for (int t = 0; t < 4; ++t)
#pragma unroll
      for (int e = 0; e < 4; ++e)
        Pb_s[w][(quad * 4 + e) * PB_STR + t * 16 + c16] = f2bf(s[t][e]);
    asm volatile("" ::: "memory");  // wave-private LDS: DS is in-order per wave
    // ---- PV: 2 j-chunks x 2 d-halves ----
#pragma unroll
    for (int jc = 0; jc < 2; ++jc) {
      short8 ap = *(const short8*)&Pb_s[w][c16 * PB_STR + jc * 32 + quad * 8];
      short8 bv0 = *(const short8*)&Vt_s[c16 * VT_STR + jc * 32 + quad * 8];
      short8 bv1 = *(const short8*)&Vt_s[(16 + c16) * VT_STR + jc * 32 + quad * 8];
      O0 = __builtin_amdgcn_mfma_f32_16x16x32_bf16(ap, bv0, O0, 0, 0, 0);
      O1 = __builtin_amdgcn_mfma_f32_16x16x32_bf16(ap, bv1, O1, 0, 0, 0);
    }
    asm volatile("" ::: "memory");
  }

#pragma unroll
  for (int e = 0; e < 4; ++e) {
    float inv = 1.0f / lrow[e];
    int row = r0w + quad * 4 + e;
    Out[(size_t)row * D + h * DK + c16] = O0[e] * inv;
    Out[(size_t)row * D + h * DK + 16 + c16] = O1[e] * inv;
  }
}

// ---------------- residual + layernorm: out = LN(x+y)*g+b ------------------
__global__ __launch_bounds__(256) void k_add_ln(const float* __restrict__ x,
                                                const float* __restrict__ y,
                                                const float* __restrict__ g,
                                                const float* __restrict__ b,
                                                float* __restrict__ outx) {
  __shared__ float s[256];
  int row = blockIdx.x, d = threadIdx.x;
  float t = x[(size_t)row * D + d] + y[(size_t)row * D + d];
  s[d] = t;
  __syncthreads();
#pragma unroll
  for (int off = 128; off; off >>= 1) {
    if (d < off) s[d] += s[d + off];
    __syncthreads();
  }
  float mean = s[0] * (1.0f / D);
  __syncthreads();
  float c = t - mean;
  s[d] = c * c;
  __syncthreads();
#pragma unroll
  for (int off = 128; off; off >>= 1) {
    if (d < off) s[d] += s[d + off];
    __syncthreads();
  }
  float var = s[0] * (1.0f / D);
  float r = rsqrtf(var + 1e-5f);
  outx[(size_t)row * D + d] = c * r * g[d] + b[d];
}

// ---------------- pool (mean & max over rows) + final projection -----------
__global__ __launch_bounds__(256) void k_pool(const float* __restrict__ x,
                                              const float* __restrict__ Wr,
                                              const float* __restrict__ br,
                                              float* __restrict__ out) {
  __shared__ float pooled[2 * D];
  int d = threadIdx.x;
  float mean = 0.f, mx = -INFINITY;
  for (int n = 0; n < N; ++n) {
    float v = x[(size_t)n * D + d];
    mean += v;
    mx = fmaxf(mx, v);
  }
  pooled[d] = mean * (1.0f / N);
  pooled[D + d] = mx;
  __syncthreads();
  float acc = br[d];
  for (int k2 = 0; k2 < 2 * D; ++k2) acc = fmaf(pooled[k2], Wr[(size_t)k2 * D + d], acc);
  out[d] = acc;
}

extern "C" void kernel_launch(void* const* d_in, const int* in_sizes, int n_in,
                              void* d_out, int out_size, void* d_ws, size_t ws_size,
                              hipStream_t stream) {
  const int* node_types = (const int*)d_in[0];
  const int* eidx = (const int*)d_in[1];
  const float* node_emb = (const float*)d_in[2];
  const float* Wq = (const float*)d_in[3];
  const float* Wk = (const float*)d_in[4];
  const float* Wv = (const float*)d_in[5];
  const float* Wo = (const float*)d_in[6];
  const float* bo = (const float*)d_in[7];
  const float* eb = (const float*)d_in[8];
  const float* W1 = (const float*)d_in[9];
  const float* b1 = (const float*)d_in[10];
  const float* W2 = (const float*)d_in[11];
  const float* b2 = (const float*)d_in[12];
  const float* g1 = (const float*)d_in[13];
  const float* be1 = (const float*)d_in[14];
  const float* g2 = (const float*)d_in[15];
  const float* be2 = (const float*)d_in[16];
  const float* Wr = (const float*)d_in[17];
  const float* br = (const float*)d_in[18];
  float* out = (float*)d_out;

  float* x = (float*)d_ws;
  float* q = x + (size_t)N * D;
  float* k = q + (size_t)N * D;
  float* v = k + (size_t)N * D;
  float* ao = v + (size_t)N * D;
  float* tmp = ao + (size_t)N * D;
  float* hb = tmp + (size_t)N * D;  // N x DFF

  k_embed<<<N, 256, 0, stream>>>(node_types, node_emb, x);

  for (int l = 0; l < L; ++l) {
    const float* wq = Wq + (size_t)l * D * D;
    const float* wk = Wk + (size_t)l * D * D;
    const float* wv = Wv + (size_t)l * D * D;
    const float* wo = Wo + (size_t)l * D * D;
    const float* w1 = W1 + (size_t)l * D * DFF;
    const float* w2 = W2 + (size_t)l * DFF * D;

    dim3 gdd(D / 64, N / 64);
    k_gemm<<<gdd, 256, 0, stream>>>(x, wq, q, N, D, D, nullptr, 0);
    k_gemm<<<gdd, 256, 0, stream>>>(x, wk, k, N, D, D, nullptr, 0);
    k_gemm<<<gdd, 256, 0, stream>>>(x, wv, v, N, D, D, nullptr, 0);

    k_attn<<<dim3(N / 32, H), 128, 0, stream>>>(q, k, v, eidx, eb + (size_t)l * NEDGE * H, ao);

    k_gemm<<<gdd, 256, 0, stream>>>(ao, wo, tmp, N, D, D, bo + (size_t)l * D, 0);
    k_add_ln<<<N, 256, 0, stream>>>(x, tmp, g1 + (size_t)l * D, be1 + (size_t)l * D, x);

    k_gemm<<<dim3(DFF / 64, N / 64), 256, 0, stream>>>(x, w1, hb, N, DFF, D, b1 + (size_t)l * DFF, 1);
    k_gemm<<<gdd, 256, 0, stream>>>(hb, w2, tmp, N, D, DFF, b2 + (size_t)l * D, 0);
    k_add_ln<<<N, 256, 0, stream>>>(x, tmp, g2 + (size_t)l * D, be2 + (size_t)l * D, x);
  }

  k_pool<<<1, 256, 0, stream>>>(x, Wr, br, out);
}

// Round 3
// 624.530 us; speedup vs baseline: 5.5724x; 2.3407x over previous
//
#include <hip/hip_runtime.h>
#include <math.h>

#define N 2048
#define D 256
#define H 8
#define DK 32
#define L 4
#define DFF 1024
#define NEDGE 5

typedef short short8 __attribute__((ext_vector_type(8)));
typedef float floatx4 __attribute__((ext_vector_type(4)));

__device__ __forceinline__ unsigned short f2bf(float f) {
  unsigned int u = __float_as_uint(f);
  u += 0x7fffu + ((u >> 16) & 1u);
  return (unsigned short)(u >> 16);
}

__device__ __forceinline__ void async16(unsigned short* lds, const unsigned short* g) {
  __builtin_amdgcn_global_load_lds(
      (const __attribute__((address_space(1))) unsigned int*)g,
      (__attribute__((address_space(3))) unsigned int*)lds, 16, 0, 0);
}

// ---- weight transpose+convert: src fp32 (K_,N_) -> dst bf16 (N_,K_) -------
__global__ __launch_bounds__(256) void k_wt(const float* __restrict__ src, size_t srcL,
                                            int K_, int N_,
                                            unsigned short* __restrict__ dst, size_t dstL,
                                            int rowOff) {
  __shared__ float t[32][33];
  int l = blockIdx.z;
  const float* s = src + (size_t)l * srcL;
  unsigned short* d = dst + (size_t)l * dstL;
  int n0 = blockIdx.x * 32, k0 = blockIdx.y * 32;
  int tx = threadIdx.x, ty = threadIdx.y;
#pragma unroll
  for (int i = 0; i < 32; i += 8) t[ty + i][tx] = s[(size_t)(k0 + ty + i) * N_ + n0 + tx];
  __syncthreads();
#pragma unroll
  for (int i = 0; i < 32; i += 8)
    d[(size_t)(rowOff + n0 + ty + i) * K_ + k0 + tx] = f2bf(t[tx][ty + i]);
}

// ---------------- embed ----------------------------------------------------
__global__ __launch_bounds__(256) void k_embed(const int* __restrict__ nt,
                                               const float* __restrict__ emb,
                                               float* __restrict__ x,
                                               unsigned short* __restrict__ xb) {
  int n = blockIdx.x, d = threadIdx.x;
  float v = emb[nt[n] * D + d];
  x[n * D + d] = v;
  xb[n * D + d] = f2bf(v);
}

// ---- bf16 MFMA GEMM: C = A(M,K) @ Bt(Nn,K)^T [+bias][+gelu] ---------------
// block 256 = 4 waves; tile 64x64; wave w does rows [w*16,w*16+16) x 64 cols.
__global__ __launch_bounds__(256) void k_mm(const unsigned short* __restrict__ A,
                                            const unsigned short* __restrict__ Bt,
                                            int Nn, int K,
                                            const float* __restrict__ bias,
                                            int gelu,
                                            float* __restrict__ outf,
                                            unsigned short* __restrict__ outb) {
  __shared__ unsigned short As[64 * 32];
  __shared__ unsigned short Bs[64 * 32];
  int tid = threadIdx.x;
  int w = tid >> 6, lane = tid & 63, quad = lane >> 4, c16 = lane & 15;
  int bm = blockIdx.y * 64, bn = blockIdx.x * 64;
  int srow = w * 16 + (lane >> 2);
  int schk = (lane & 3) * 8;
  const unsigned short* gA = A + (size_t)(bm + srow) * K + schk;
  const unsigned short* gB = Bt + (size_t)(bn + srow) * K + schk;
  unsigned short* lA = &As[w * 512 + lane * 8];
  unsigned short* lB = &Bs[w * 512 + lane * 8];

  floatx4 acc[4] = {{0.f, 0.f, 0.f, 0.f}, {0.f, 0.f, 0.f, 0.f},
                    {0.f, 0.f, 0.f, 0.f}, {0.f, 0.f, 0.f, 0.f}};
  for (int k0 = 0; k0 < K; k0 += 32) {
    async16(lA, gA + k0);
    async16(lB, gB + k0);
    __syncthreads();
    short8 a = *(const short8*)&As[(w * 16 + c16) * 32 + quad * 8];
#pragma unroll
    for (int nt = 0; nt < 4; ++nt) {
      short8 b = *(const short8*)&Bs[(nt * 16 + c16) * 32 + quad * 8];
      acc[nt] = __builtin_amdgcn_mfma_f32_16x16x32_bf16(a, b, acc[nt], 0, 0, 0);
    }
    __syncthreads();
  }
#pragma unroll
  for (int nt = 0; nt < 4; ++nt) {
#pragma unroll
    for (int e = 0; e < 4; ++e) {
      int row = bm + w * 16 + quad * 4 + e;
      int col = bn + nt * 16 + c16;
      float v = acc[nt][e] + bias[col];
      if (gelu) v = 0.5f * v * (1.0f + erff(v * 0.70710678118654752f));
      if (outf) outf[(size_t)row * Nn + col] = v;
      if (outb) outb[(size_t)row * Nn + col] = f2bf(v);
    }
  }
}

// ---- fused QKV GEMM: Nn=768; writes qb,kb (N,D) bf16 and vt (D,N) bf16 ----
__global__ __launch_bounds__(256) void k_mm_qkv(const unsigned short* __restrict__ A,
                                                const unsigned short* __restrict__ Bt,
                                                unsigned short* __restrict__ qb,
                                                unsigned short* __restrict__ kb,
                                                unsigned short* __restrict__ vtb) {
  const int K = D, Nn = 768;
  __shared__ unsigned short As[64 * 32];
  __shared__ unsigned short Bs[64 * 32];
  int tid = threadIdx.x;
  int w = tid >> 6, lane = tid & 63, quad = lane >> 4, c16 = lane & 15;
  int bm = blockIdx.y * 64, bn = blockIdx.x * 64;
  int srow = w * 16 + (lane >> 2);
  int schk = (lane & 3) * 8;
  const unsigned short* gA = A + (size_t)(bm + srow) * K + schk;
  const unsigned short* gB = Bt + (size_t)(bn + srow) * K + schk;
  unsigned short* lA = &As[w * 512 + lane * 8];
  unsigned short* lB = &Bs[w * 512 + lane * 8];

  floatx4 acc[4] = {{0.f, 0.f, 0.f, 0.f}, {0.f, 0.f, 0.f, 0.f},
                    {0.f, 0.f, 0.f, 0.f}, {0.f, 0.f, 0.f, 0.f}};
  for (int k0 = 0; k0 < K; k0 += 32) {
    async16(lA, gA + k0);
    async16(lB, gB + k0);
    __syncthreads();
    short8 a = *(const short8*)&As[(w * 16 + c16) * 32 + quad * 8];
#pragma unroll
    for (int nt = 0; nt < 4; ++nt) {
      short8 b = *(const short8*)&Bs[(nt * 16 + c16) * 32 + quad * 8];
      acc[nt] = __builtin_amdgcn_mfma_f32_16x16x32_bf16(a, b, acc[nt], 0, 0, 0);
    }
    __syncthreads();
  }
#pragma unroll
  for (int nt = 0; nt < 4; ++nt) {
#pragma unroll
    for (int e = 0; e < 4; ++e) {
      int row = bm + w * 16 + quad * 4 + e;
      int col = bn + nt * 16 + c16;  // 0..767 (q:0-255, k:256-511, v:512-767)
      unsigned short bv = f2bf(acc[nt][e]);
      if (col < 512) {
        unsigned short* dst = (col < 256) ? qb : kb;
        dst[(size_t)row * D + (col & 255)] = bv;
      } else {
        vtb[(size_t)(col - 512) * N + row] = bv;
      }
    }
  }
}

// ---- MFMA flash attention, LDS-free K/V (direct bf16 global frags) --------
// block = 512 (8 waves); wave h handles head h for the block's 16 Q-rows.
#define PB_STR 72
__global__ __launch_bounds__(512) void k_attn(const unsigned short* __restrict__ qb,
                                              const unsigned short* __restrict__ kb,
                                              const unsigned short* __restrict__ vt,
                                              const int* __restrict__ eidx,
                                              const float* __restrict__ eb,
                                              unsigned short* __restrict__ aob) {
  __shared__ unsigned short Pb[H][16 * PB_STR];
  __shared__ float ebh[H][NEDGE];
  const int tid = threadIdx.x;
  const int h = tid >> 6;
  const int lane = tid & 63;
  const int quad = lane >> 4;
  const int c16 = lane & 15;
  const int r0 = blockIdx.x * 16;

  if (tid < NEDGE * H) ebh[tid % H][tid / H] = eb[tid];
  __syncthreads();

  short8 aq = *(const short8*)&qb[(size_t)(r0 + c16) * D + h * DK + quad * 8];

  float mrow[4] = {-INFINITY, -INFINITY, -INFINITY, -INFINITY};
  float lrow[4] = {0.f, 0.f, 0.f, 0.f};
  floatx4 O0 = {0.f, 0.f, 0.f, 0.f};
  floatx4 O1 = {0.f, 0.f, 0.f, 0.f};
  const float scale = 0.17677669529663688f;

  for (int j0 = 0; j0 < N; j0 += 64) {
    // ---- QK^T: B-frag direct from kb (bf16, row-major) ----
    floatx4 Sc[4];
#pragma unroll
    for (int t = 0; t < 4; ++t) {
      short8 bk = *(const short8*)&kb[(size_t)(j0 + t * 16 + c16) * D + h * DK + quad * 8];
      floatx4 z = {0.f, 0.f, 0.f, 0.f};
      Sc[t] = __builtin_amdgcn_mfma_f32_16x16x32_bf16(aq, bk, z, 0, 0, 0);
    }
    float s[4][4];
#pragma unroll
    for (int t = 0; t < 4; ++t) {
#pragma unroll
      for (int e = 0; e < 4; ++e) {
        int ei = eidx[(size_t)(r0 + quad * 4 + e) * N + j0 + t * 16 + c16];
        s[t][e] = Sc[t][e] * scale + ebh[h][ei];
      }
    }
#pragma unroll
    for (int e = 0; e < 4; ++e) {
      float tm = fmaxf(fmaxf(s[0][e], s[1][e]), fmaxf(s[2][e], s[3][e]));
      tm = fmaxf(tm, __shfl_xor(tm, 1));
      tm = fmaxf(tm, __shfl_xor(tm, 2));
      tm = fmaxf(tm, __shfl_xor(tm, 4));
      tm = fmaxf(tm, __shfl_xor(tm, 8));
      float mn = fmaxf(mrow[e], tm);
      float alpha = __expf(mrow[e] - mn);
      mrow[e] = mn;
      float ps = 0.f;
#pragma unroll
      for (int t = 0; t < 4; ++t) {
        float p = __expf(s[t][e] - mn);
        s[t][e] = p;
        ps += p;
      }
      ps += __shfl_xor(ps, 1);
      ps += __shfl_xor(ps, 2);
      ps += __shfl_xor(ps, 4);
      ps += __shfl_xor(ps, 8);
      lrow[e] = lrow[e] * alpha + ps;
      O0[e] *= alpha;
      O1[e] *= alpha;
    }
    // ---- P (C-layout) -> wave-private LDS -> A-layout ----
#pragma unroll
    for (int t = 0; t < 4; ++t)
#pragma unroll
      for (int e = 0; e < 4; ++e)
        Pb[h][(quad * 4 + e) * PB_STR + t * 16 + c16] = f2bf(s[t][e]);
    asm volatile("" ::: "memory");
    // ---- PV: B-frag direct from vt (d-major, bf16) ----
#pragma unroll
    for (int jc = 0; jc < 2; ++jc) {
      short8 ap = *(const short8*)&Pb[h][c16 * PB_STR + jc * 32 + quad * 8];
      short8 bv0 = *(const short8*)&vt[(size_t)(h * DK + c16) * N + j0 + jc * 32 + quad * 8];
      short8 bv1 = *(const short8*)&vt[(size_t)(h * DK + 16 + c16) * N + j0 + jc * 32 + quad * 8];
      O0 = __builtin_amdgcn_mfma_f32_16x16x32_bf16(ap, bv0, O0, 0, 0, 0);
      O1 = __builtin_amdgcn_mfma_f32_16x16x32_bf16(ap, bv1, O1, 0, 0, 0);
    }
    asm volatile("" ::: "memory");
  }

#pragma unroll
  for (int e = 0; e < 4; ++e) {
    float inv = 1.0f / lrow[e];
    int row = r0 + quad * 4 + e;
    aob[(size_t)row * D + h * DK + c16] = f2bf(O0[e] * inv);
    aob[(size_t)row * D + h * DK + 16 + c16] = f2bf(O1[e] * inv);
  }
}

// ---- residual + layernorm; writes fp32 master + bf16 copy -----------------
__global__ __launch_bounds__(256) void k_add_ln(const float* __restrict__ x,
                                                const float* __restrict__ y,
                                                const float* __restrict__ g,
                                                const float* __restrict__ b,
                                                float* __restrict__ outx,
                                                unsigned short* __restrict__ outb) {
  __shared__ float s[256];
  int row = blockIdx.x, d = threadIdx.x;
  float t = x[(size_t)row * D + d] + y[(size_t)row * D + d];
  s[d] = t;
  __syncthreads();
#pragma unroll
  for (int off = 128; off; off >>= 1) {
    if (d < off) s[d] += s[d + off];
    __syncthreads();
  }
  float mean = s[0] * (1.0f / D);
  __syncthreads();
  float c = t - mean;
  s[d] = c * c;
  __syncthreads();
#pragma unroll
  for (int off = 128; off; off >>= 1) {
    if (d < off) s[d] += s[d + off];
    __syncthreads();
  }
  float var = s[0] * (1.0f / D);
  float r = rsqrtf(var + 1e-5f);
  float o = c * r * g[d] + b[d];
  outx[(size_t)row * D + d] = o;
  outb[(size_t)row * D + d] = f2bf(o);
}

// ---- pool + final projection ----------------------------------------------
__global__ __launch_bounds__(256) void k_pool(const float* __restrict__ x,
                                              const float* __restrict__ Wr,
                                              const float* __restrict__ br,
                                              float* __restrict__ out) {
  __shared__ float pooled[2 * D];
  int d = threadIdx.x;
  float mean = 0.f, mx = -INFINITY;
  for (int n = 0; n < N; ++n) {
    float v = x[(size_t)n * D + d];
    mean += v;
    mx = fmaxf(mx, v);
  }
  pooled[d] = mean * (1.0f / N);
  pooled[D + d] = mx;
  __syncthreads();
  float acc = br[d];
  for (int k2 = 0; k2 < 2 * D; ++k2) acc = fmaf(pooled[k2], Wr[(size_t)k2 * D + d], acc);
  out[d] = acc;
}

extern "C" void kernel_launch(void* const* d_in, const int* in_sizes, int n_in,
                              void* d_out, int out_size, void* d_ws, size_t ws_size,
                              hipStream_t stream) {
  const int* node_types = (const int*)d_in[0];
  const int* eidx = (const int*)d_in[1];
  const float* node_emb = (const float*)d_in[2];
  const float* Wq = (const float*)d_in[3];
  const float* Wk = (const float*)d_in[4];
  const float* Wv = (const float*)d_in[5];
  const float* Wo = (const float*)d_in[6];
  const float* bo = (const float*)d_in[7];
  const float* eb = (const float*)d_in[8];
  const float* W1 = (const float*)d_in[9];
  const float* b1 = (const float*)d_in[10];
  const float* W2 = (const float*)d_in[11];
  const float* b2 = (const float*)d_in[12];
  const float* g1 = (const float*)d_in[13];
  const float* be1 = (const float*)d_in[14];
  const float* g2 = (const float*)d_in[15];
  const float* be2 = (const float*)d_in[16];
  const float* Wr = (const float*)d_in[17];
  const float* br = (const float*)d_in[18];
  float* out = (float*)d_out;

  // workspace layout
  float* x = (float*)d_ws;                      // N*D fp32
  float* tmp = x + (size_t)N * D;               // N*D fp32
  unsigned short* xb = (unsigned short*)(tmp + (size_t)N * D);
  unsigned short* qb = xb + (size_t)N * D;
  unsigned short* kb = qb + (size_t)N * D;
  unsigned short* vtb = kb + (size_t)N * D;     // (D, N) head-major d
  unsigned short* aob = vtb + (size_t)N * D;
  unsigned short* hb = aob + (size_t)N * D;     // N*DFF
  unsigned short* wqkvb = hb + (size_t)N * DFF; // L x (768, 256)
  unsigned short* wob = wqkvb + (size_t)L * 768 * D;   // L x (256, 256)
  unsigned short* w1b = wob + (size_t)L * D * D;       // L x (1024, 256)
  unsigned short* w2b = w1b + (size_t)L * DFF * D;     // L x (256, 1024)

  // weight convert+transpose (all layers)
  dim3 tb(32, 8);
  k_wt<<<dim3(D / 32, D / 32, L), tb, 0, stream>>>(Wq, (size_t)D * D, D, D, wqkvb, 768 * D, 0);
  k_wt<<<dim3(D / 32, D / 32, L), tb, 0, stream>>>(Wk, (size_t)D * D, D, D, wqkvb, 768 * D, 256);
  k_wt<<<dim3(D / 32, D / 32, L), tb, 0, stream>>>(Wv, (size_t)D * D, D, D, wqkvb, 768 * D, 512);
  k_wt<<<dim3(D / 32, D / 32, L), tb, 0, stream>>>(Wo, (size_t)D * D, D, D, wob, D * D, 0);
  k_wt<<<dim3(DFF / 32, D / 32, L), tb, 0, stream>>>(W1, (size_t)D * DFF, D, DFF, w1b, DFF * D, 0);
  k_wt<<<dim3(D / 32, DFF / 32, L), tb, 0, stream>>>(W2, (size_t)DFF * D, DFF, D, w2b, D * DFF, 0);

  k_embed<<<N, 256, 0, stream>>>(node_types, node_emb, x, xb);

  for (int l = 0; l < L; ++l) {
    k_mm_qkv<<<dim3(768 / 64, N / 64), 256, 0, stream>>>(
        xb, wqkvb + (size_t)l * 768 * D, qb, kb, vtb);

    k_attn<<<N / 16, 512, 0, stream>>>(qb, kb, vtb, eidx, eb + (size_t)l * NEDGE * H, aob);

    k_mm<<<dim3(D / 64, N / 64), 256, 0, stream>>>(
        aob, wob + (size_t)l * D * D, D, D, bo + (size_t)l * D, 0, tmp, (unsigned short*)nullptr);
    k_add_ln<<<N, 256, 0, stream>>>(x, tmp, g1 + (size_t)l * D, be1 + (size_t)l * D, x, xb);

    k_mm<<<dim3(DFF / 64, N / 64), 256, 0, stream>>>(
        xb, w1b + (size_t)l * DFF * D, DFF, D, b1 + (size_t)l * DFF, 1, (float*)nullptr, hb);
    k_mm<<<dim3(D / 64, N / 64), 256, 0, stream>>>(
        hb, w2b + (size_t)l * D * DFF, D, DFF, b2 + (size_t)l * D, 0, tmp, (unsigned short*)nullptr);
    k_add_ln<<<N, 256, 0, stream>>>(x, tmp, g2 + (size_t)l * D, be2 + (size_t)l * D, x, xb);
  }

  k_pool<<<1, 256, 0, stream>>>(x, Wr, br, out);
}

// Round 4
// 482.963 us; speedup vs baseline: 7.2058x; 1.2931x over previous
//
#include <hip/hip_runtime.h>
#include <math.h>

#define N 2048
#define D 256
#define H 8
#define DK 32
#define L 4
#define DFF 1024
#define NEDGE 5
#define JC 4  // attention j-chunks (flash-decode split)

typedef short short8 __attribute__((ext_vector_type(8)));
typedef float floatx4 __attribute__((ext_vector_type(4)));

__device__ __forceinline__ unsigned short f2bf(float f) {
  unsigned int u = __float_as_uint(f);
  u += 0x7fffu + ((u >> 16) & 1u);
  return (unsigned short)(u >> 16);
}

__device__ __forceinline__ void async16(unsigned short* lds, const unsigned short* g) {
  __builtin_amdgcn_global_load_lds(
      (const __attribute__((address_space(1))) unsigned int*)g,
      (__attribute__((address_space(3))) unsigned int*)lds, 16, 0, 0);
}

// ---- eidx int32 -> uint8 (4x less gather traffic; L2/L3-resident) ---------
__global__ __launch_bounds__(256) void k_e8(const int* __restrict__ e,
                                            unsigned int* __restrict__ e8) {
  int i = blockIdx.x * 256 + threadIdx.x;  // over N*N/4
  int4 v = ((const int4*)e)[i];
  e8[i] = (unsigned int)(v.x & 0xff) | ((unsigned int)(v.y & 0xff) << 8) |
          ((unsigned int)(v.z & 0xff) << 16) | ((unsigned int)(v.w & 0xff) << 24);
}

// ---- weight transpose+convert: src fp32 (K_,N_) -> dst bf16 (N_,K_) -------
__global__ __launch_bounds__(256) void k_wt(const float* __restrict__ src, size_t srcL,
                                            int K_, int N_,
                                            unsigned short* __restrict__ dst, size_t dstL,
                                            int rowOff) {
  __shared__ float t[32][33];
  int l = blockIdx.z;
  const float* s = src + (size_t)l * srcL;
  unsigned short* d = dst + (size_t)l * dstL;
  int n0 = blockIdx.x * 32, k0 = blockIdx.y * 32;
  int tx = threadIdx.x, ty = threadIdx.y;
#pragma unroll
  for (int i = 0; i < 32; i += 8) t[ty + i][tx] = s[(size_t)(k0 + ty + i) * N_ + n0 + tx];
  __syncthreads();
#pragma unroll
  for (int i = 0; i < 32; i += 8)
    d[(size_t)(rowOff + n0 + ty + i) * K_ + k0 + tx] = f2bf(t[tx][ty + i]);
}

// ---------------- embed ----------------------------------------------------
__global__ __launch_bounds__(256) void k_embed(const int* __restrict__ nt,
                                               const float* __restrict__ emb,
                                               float* __restrict__ x,
                                               unsigned short* __restrict__ xb) {
  int n = blockIdx.x, d = threadIdx.x;
  float v = emb[nt[n] * D + d];
  x[n * D + d] = v;
  xb[n * D + d] = f2bf(v);
}

// ---- bf16 MFMA GEMM: C = A(M,K) @ Bt(Nn,K)^T [+bias][+gelu] ---------------
__global__ __launch_bounds__(256) void k_mm(const unsigned short* __restrict__ A,
                                            const unsigned short* __restrict__ Bt,
                                            int Nn, int K,
                                            const float* __restrict__ bias,
                                            int gelu,
                                            float* __restrict__ outf,
                                            unsigned short* __restrict__ outb) {
  __shared__ unsigned short As[64 * 32];
  __shared__ unsigned short Bs[64 * 32];
  int tid = threadIdx.x;
  int w = tid >> 6, lane = tid & 63, quad = lane >> 4, c16 = lane & 15;
  int bm = blockIdx.y * 64, bn = blockIdx.x * 64;
  int srow = w * 16 + (lane >> 2);
  int schk = (lane & 3) * 8;
  const unsigned short* gA = A + (size_t)(bm + srow) * K + schk;
  const unsigned short* gB = Bt + (size_t)(bn + srow) * K + schk;
  unsigned short* lA = &As[w * 512 + lane * 8];
  unsigned short* lB = &Bs[w * 512 + lane * 8];

  floatx4 acc[4] = {{0.f, 0.f, 0.f, 0.f}, {0.f, 0.f, 0.f, 0.f},
                    {0.f, 0.f, 0.f, 0.f}, {0.f, 0.f, 0.f, 0.f}};
  for (int k0 = 0; k0 < K; k0 += 32) {
    async16(lA, gA + k0);
    async16(lB, gB + k0);
    __syncthreads();
    short8 a = *(const short8*)&As[(w * 16 + c16) * 32 + quad * 8];
#pragma unroll
    for (int nt = 0; nt < 4; ++nt) {
      short8 b = *(const short8*)&Bs[(nt * 16 + c16) * 32 + quad * 8];
      acc[nt] = __builtin_amdgcn_mfma_f32_16x16x32_bf16(a, b, acc[nt], 0, 0, 0);
    }
    __syncthreads();
  }
#pragma unroll
  for (int nt = 0; nt < 4; ++nt) {
#pragma unroll
    for (int e = 0; e < 4; ++e) {
      int row = bm + w * 16 + quad * 4 + e;
      int col = bn + nt * 16 + c16;
      float v = acc[nt][e] + bias[col];
      if (gelu) v = 0.5f * v * (1.0f + erff(v * 0.70710678118654752f));
      if (outf) outf[(size_t)row * Nn + col] = v;
      if (outb) outb[(size_t)row * Nn + col] = f2bf(v);
    }
  }
}

// ---- fused QKV GEMM: Nn=768; writes qb,kb (N,D) bf16 and vt (D,N) bf16 ----
__global__ __launch_bounds__(256) void k_mm_qkv(const unsigned short* __restrict__ A,
                                                const unsigned short* __restrict__ Bt,
                                                unsigned short* __restrict__ qb,
                                                unsigned short* __restrict__ kb,
                                                unsigned short* __restrict__ vtb) {
  const int K = D;
  __shared__ unsigned short As[64 * 32];
  __shared__ unsigned short Bs[64 * 32];
  int tid = threadIdx.x;
  int w = tid >> 6, lane = tid & 63, quad = lane >> 4, c16 = lane & 15;
  int bm = blockIdx.y * 64, bn = blockIdx.x * 64;
  int srow = w * 16 + (lane >> 2);
  int schk = (lane & 3) * 8;
  const unsigned short* gA = A + (size_t)(bm + srow) * K + schk;
  const unsigned short* gB = Bt + (size_t)(bn + srow) * K + schk;
  unsigned short* lA = &As[w * 512 + lane * 8];
  unsigned short* lB = &Bs[w * 512 + lane * 8];

  floatx4 acc[4] = {{0.f, 0.f, 0.f, 0.f}, {0.f, 0.f, 0.f, 0.f},
                    {0.f, 0.f, 0.f, 0.f}, {0.f, 0.f, 0.f, 0.f}};
  for (int k0 = 0; k0 < K; k0 += 32) {
    async16(lA, gA + k0);
    async16(lB, gB + k0);
    __syncthreads();
    short8 a = *(const short8*)&As[(w * 16 + c16) * 32 + quad * 8];
#pragma unroll
    for (int nt = 0; nt < 4; ++nt) {
      short8 b = *(const short8*)&Bs[(nt * 16 + c16) * 32 + quad * 8];
      acc[nt] = __builtin_amdgcn_mfma_f32_16x16x32_bf16(a, b, acc[nt], 0, 0, 0);
    }
    __syncthreads();
  }
#pragma unroll
  for (int nt = 0; nt < 4; ++nt) {
#pragma unroll
    for (int e = 0; e < 4; ++e) {
      int row = bm + w * 16 + quad * 4 + e;
      int col = bn + nt * 16 + c16;  // q:0-255, k:256-511, v:512-767
      unsigned short bv = f2bf(acc[nt][e]);
      if (col < 512) {
        unsigned short* dst = (col < 256) ? qb : kb;
        dst[(size_t)row * D + (col & 255)] = bv;
      } else {
        vtb[(size_t)(col - 512) * N + row] = bv;
      }
    }
  }
}

// ---- MFMA flash attention, j-split partials -------------------------------
// grid (N/16, JC); block 512 (8 waves); wave h = head h, 16 Q-rows, 512 cols.
#define PB_STR 72
__global__ __launch_bounds__(512) void k_attn(const unsigned short* __restrict__ qb,
                                              const unsigned short* __restrict__ kb,
                                              const unsigned short* __restrict__ vt,
                                              const unsigned char* __restrict__ e8,
                                              const float* __restrict__ eb,
                                              float* __restrict__ Opart,
                                              float* __restrict__ mpart,
                                              float* __restrict__ lpart) {
  __shared__ unsigned short Pb[H][16 * PB_STR];
  __shared__ float ebh[H][NEDGE];
  const int tid = threadIdx.x;
  const int h = tid >> 6;
  const int lane = tid & 63;
  const int quad = lane >> 4;
  const int c16 = lane & 15;
  const int r0 = blockIdx.x * 16;
  const int jc = blockIdx.y;

  if (tid < NEDGE * H) ebh[tid % H][tid / H] = eb[tid];
  __syncthreads();

  short8 aq = *(const short8*)&qb[(size_t)(r0 + c16) * D + h * DK + quad * 8];

  float mrow[4] = {-INFINITY, -INFINITY, -INFINITY, -INFINITY};
  float lrow[4] = {0.f, 0.f, 0.f, 0.f};
  floatx4 O0 = {0.f, 0.f, 0.f, 0.f};
  floatx4 O1 = {0.f, 0.f, 0.f, 0.f};
  const float scale = 0.17677669529663688f;

  for (int j0 = jc * (N / JC); j0 < (jc + 1) * (N / JC); j0 += 64) {
    floatx4 Sc[4];
#pragma unroll
    for (int t = 0; t < 4; ++t) {
      short8 bk = *(const short8*)&kb[(size_t)(j0 + t * 16 + c16) * D + h * DK + quad * 8];
      floatx4 z = {0.f, 0.f, 0.f, 0.f};
      Sc[t] = __builtin_amdgcn_mfma_f32_16x16x32_bf16(aq, bk, z, 0, 0, 0);
    }
    float s[4][4];
#pragma unroll
    for (int t = 0; t < 4; ++t) {
#pragma unroll
      for (int e = 0; e < 4; ++e) {
        int ei = e8[(size_t)(r0 + quad * 4 + e) * N + j0 + t * 16 + c16];
        s[t][e] = Sc[t][e] * scale + ebh[h][ei];
      }
    }
#pragma unroll
    for (int e = 0; e < 4; ++e) {
      float tm = fmaxf(fmaxf(s[0][e], s[1][e]), fmaxf(s[2][e], s[3][e]));
      tm = fmaxf(tm, __shfl_xor(tm, 1));
      tm = fmaxf(tm, __shfl_xor(tm, 2));
      tm = fmaxf(tm, __shfl_xor(tm, 4));
      tm = fmaxf(tm, __shfl_xor(tm, 8));
      float mn = fmaxf(mrow[e], tm);
      float alpha = __expf(mrow[e] - mn);
      mrow[e] = mn;
      float ps = 0.f;
#pragma unroll
      for (int t = 0; t < 4; ++t) {
        float p = __expf(s[t][e] - mn);
        s[t][e] = p;
        ps += p;
      }
      ps += __shfl_xor(ps, 1);
      ps += __shfl_xor(ps, 2);
      ps += __shfl_xor(ps, 4);
      ps += __shfl_xor(ps, 8);
      lrow[e] = lrow[e] * alpha + ps;
      O0[e] *= alpha;
      O1[e] *= alpha;
    }
#pragma unroll
    for (int t = 0; t < 4; ++t)
#pragma unroll
      for (int e = 0; e < 4; ++e)
        Pb[h][(quad * 4 + e) * PB_STR + t * 16 + c16] = f2bf(s[t][e]);
    asm volatile("" ::: "memory");
#pragma unroll
    for (int jj = 0; jj < 2; ++jj) {
      short8 ap = *(const short8*)&Pb[h][c16 * PB_STR + jj * 32 + quad * 8];
      short8 bv0 = *(const short8*)&vt[(size_t)(h * DK + c16) * N + j0 + jj * 32 + quad * 8];
      short8 bv1 = *(const short8*)&vt[(size_t)(h * DK + 16 + c16) * N + j0 + jj * 32 + quad * 8];
      O0 = __builtin_amdgcn_mfma_f32_16x16x32_bf16(ap, bv0, O0, 0, 0, 0);
      O1 = __builtin_amdgcn_mfma_f32_16x16x32_bf16(ap, bv1, O1, 0, 0, 0);
    }
    asm volatile("" ::: "memory");
  }

  // unnormalized partials
#pragma unroll
  for (int e = 0; e < 4; ++e) {
    int row = r0 + quad * 4 + e;
    size_t ob = ((size_t)jc * N + row) * D + h * DK;
    Opart[ob + c16] = O0[e];
    Opart[ob + 16 + c16] = O1[e];
    if (c16 == 0) {
      mpart[((size_t)jc * N + row) * H + h] = mrow[e];
      lpart[((size_t)jc * N + row) * H + h] = lrow[e];
    }
  }
}

// ---- combine JC partial chunks -> attention output (bf16) -----------------
__global__ __launch_bounds__(256) void k_attn_comb(const float* __restrict__ Opart,
                                                   const float* __restrict__ mpart,
                                                   const float* __restrict__ lpart,
                                                   unsigned short* __restrict__ aob) {
  int row = blockIdx.x, d = threadIdx.x, h = d >> 5;
  float m[JC];
  float mstar = -INFINITY;
#pragma unroll
  for (int c = 0; c < JC; ++c) {
    m[c] = mpart[((size_t)c * N + row) * H + h];
    mstar = fmaxf(mstar, m[c]);
  }
  float lstar = 0.f, o = 0.f;
#pragma unroll
  for (int c = 0; c < JC; ++c) {
    float wgt = __expf(m[c] - mstar);
    lstar += wgt * lpart[((size_t)c * N + row) * H + h];
    o += wgt * Opart[((size_t)c * N + row) * D + d];
  }
  aob[(size_t)row * D + d] = f2bf(o / lstar);
}

// ---- residual + layernorm; writes fp32 master + bf16 copy -----------------
__global__ __launch_bounds__(256) void k_add_ln(const float* __restrict__ x,
                                                const float* __restrict__ y,
                                                const float* __restrict__ g,
                                                const float* __restrict__ b,
                                                float* __restrict__ outx,
                                                unsigned short* __restrict__ outb) {
  __shared__ float s[256];
  int row = blockIdx.x, d = threadIdx.x;
  float t = x[(size_t)row * D + d] + y[(size_t)row * D + d];
  s[d] = t;
  __syncthreads();
#pragma unroll
  for (int off = 128; off; off >>= 1) {
    if (d < off) s[d] += s[d + off];
    __syncthreads();
  }
  float mean = s[0] * (1.0f / D);
  __syncthreads();
  float c = t - mean;
  s[d] = c * c;
  __syncthreads();
#pragma unroll
  for (int off = 128; off; off >>= 1) {
    if (d < off) s[d] += s[d + off];
    __syncthreads();
  }
  float var = s[0] * (1.0f / D);
  float r = rsqrtf(var + 1e-5f);
  float o = c * r * g[d] + b[d];
  outx[(size_t)row * D + d] = o;
  outb[(size_t)row * D + d] = f2bf(o);
}

// ---- pool phase 1: 64 blocks x 32 rows -> partial sum/max -----------------
__global__ __launch_bounds__(256) void k_pool1(const float* __restrict__ x,
                                               float* __restrict__ part) {
  int b = blockIdx.x, d = threadIdx.x;
  float sum = 0.f, mx = -INFINITY;
  for (int n = b * 32; n < b * 32 + 32; ++n) {
    float v = x[(size_t)n * D + d];
    sum += v;
    mx = fmaxf(mx, v);
  }
  part[(size_t)b * 2 * D + d] = sum;
  part[(size_t)b * 2 * D + D + d] = mx;
}

// ---- pool phase 2: reduce 64 partials + project ---------------------------
__global__ __launch_bounds__(256) void k_pool2(const float* __restrict__ part,
                                               const float* __restrict__ Wr,
                                               const float* __restrict__ br,
                                               float* __restrict__ out) {
  __shared__ float pooled[2 * D];
  int d = threadIdx.x;
  float sum = 0.f, mx = -INFINITY;
  for (int b = 0; b < 64; ++b) {
    sum += part[(size_t)b * 2 * D + d];
    mx = fmaxf(mx, part[(size_t)b * 2 * D + D + d]);
  }
  pooled[d] = sum * (1.0f / N);
  pooled[D + d] = mx;
  __syncthreads();
  float acc = br[d];
  for (int k2 = 0; k2 < 2 * D; ++k2) acc = fmaf(pooled[k2], Wr[(size_t)k2 * D + d], acc);
  out[d] = acc;
}

extern "C" void kernel_launch(void* const* d_in, const int* in_sizes, int n_in,
                              void* d_out, int out_size, void* d_ws, size_t ws_size,
                              hipStream_t stream) {
  const int* node_types = (const int*)d_in[0];
  const int* eidx = (const int*)d_in[1];
  const float* node_emb = (const float*)d_in[2];
  const float* Wq = (const float*)d_in[3];
  const float* Wk = (const float*)d_in[4];
  const float* Wv = (const float*)d_in[5];
  const float* Wo = (const float*)d_in[6];
  const float* bo = (const float*)d_in[7];
  const float* eb = (const float*)d_in[8];
  const float* W1 = (const float*)d_in[9];
  const float* b1 = (const float*)d_in[10];
  const float* W2 = (const float*)d_in[11];
  const float* b2 = (const float*)d_in[12];
  const float* g1 = (const float*)d_in[13];
  const float* be1 = (const float*)d_in[14];
  const float* g2 = (const float*)d_in[15];
  const float* be2 = (const float*)d_in[16];
  const float* Wr = (const float*)d_in[17];
  const float* br = (const float*)d_in[18];
  float* out = (float*)d_out;

  // workspace layout
  float* x = (float*)d_ws;                      // N*D fp32
  float* tmp = x + (size_t)N * D;               // N*D fp32
  float* Opart = tmp + (size_t)N * D;           // JC*N*D fp32
  float* mpart = Opart + (size_t)JC * N * D;    // JC*N*H
  float* lpart = mpart + (size_t)JC * N * H;    // JC*N*H
  float* ppool = lpart + (size_t)JC * N * H;    // 64*2*D
  unsigned short* xb = (unsigned short*)(ppool + 64 * 2 * D);
  unsigned short* qb = xb + (size_t)N * D;
  unsigned short* kb = qb + (size_t)N * D;
  unsigned short* vtb = kb + (size_t)N * D;     // (D, N) head-major d
  unsigned short* aob = vtb + (size_t)N * D;
  unsigned short* hb = aob + (size_t)N * D;     // N*DFF
  unsigned short* wqkvb = hb + (size_t)N * DFF; // L x (768, 256)
  unsigned short* wob = wqkvb + (size_t)L * 768 * D;
  unsigned short* w1b = wob + (size_t)L * D * D;
  unsigned short* w2b = w1b + (size_t)L * DFF * D;
  unsigned char* e8 = (unsigned char*)(w2b + (size_t)L * D * DFF);  // N*N bytes

  k_e8<<<(N * N / 4) / 256, 256, 0, stream>>>(eidx, (unsigned int*)e8);

  dim3 tb(32, 8);
  k_wt<<<dim3(D / 32, D / 32, L), tb, 0, stream>>>(Wq, (size_t)D * D, D, D, wqkvb, 768 * D, 0);
  k_wt<<<dim3(D / 32, D / 32, L), tb, 0, stream>>>(Wk, (size_t)D * D, D, D, wqkvb, 768 * D, 256);
  k_wt<<<dim3(D / 32, D / 32, L), tb, 0, stream>>>(Wv, (size_t)D * D, D, D, wqkvb, 768 * D, 512);
  k_wt<<<dim3(D / 32, D / 32, L), tb, 0, stream>>>(Wo, (size_t)D * D, D, D, wob, D * D, 0);
  k_wt<<<dim3(DFF / 32, D / 32, L), tb, 0, stream>>>(W1, (size_t)D * DFF, D, DFF, w1b, DFF * D, 0);
  k_wt<<<dim3(D / 32, DFF / 32, L), tb, 0, stream>>>(W2, (size_t)DFF * D, DFF, D, w2b, D * DFF, 0);

  k_embed<<<N, 256, 0, stream>>>(node_types, node_emb, x, xb);

  for (int l = 0; l < L; ++l) {
    k_mm_qkv<<<dim3(768 / 64, N / 64), 256, 0, stream>>>(
        xb, wqkvb + (size_t)l * 768 * D, qb, kb, vtb);

    k_attn<<<dim3(N / 16, JC), 512, 0, stream>>>(qb, kb, vtb, e8,
                                                 eb + (size_t)l * NEDGE * H,
                                                 Opart, mpart, lpart);
    k_attn_comb<<<N, 256, 0, stream>>>(Opart, mpart, lpart, aob);

    k_mm<<<dim3(D / 64, N / 64), 256, 0, stream>>>(
        aob, wob + (size_t)l * D * D, D, D, bo + (size_t)l * D, 0, tmp, (unsigned short*)nullptr);
    k_add_ln<<<N, 256, 0, stream>>>(x, tmp, g1 + (size_t)l * D, be1 + (size_t)l * D, x, xb);

    k_mm<<<dim3(DFF / 64, N / 64), 256, 0, stream>>>(
        xb, w1b + (size_t)l * DFF * D, DFF, D, b1 + (size_t)l * DFF, 1, (float*)nullptr, hb);
    k_mm<<<dim3(D / 64, N / 64), 256, 0, stream>>>(
        hb, w2b + (size_t)l * D * DFF, D, DFF, b2 + (size_t)l * D, 0, tmp, (unsigned short*)nullptr);
    k_add_ln<<<N, 256, 0, stream>>>(x, tmp, g2 + (size_t)l * D, be2 + (size_t)l * D, x, xb);
  }

  k_pool1<<<64, 256, 0, stream>>>(x, ppool);
  k_pool2<<<1, 256, 0, stream>>>(ppool, Wr, br, out);
}